// Round 1
// baseline (668.808 us; speedup 1.0000x reference)
//
#include <hip/hip_runtime.h>
#include <hip/hip_bf16.h>
#include <math.h>

#define N_NODES 50000
#define N_EDGES 800000
#define N_GRAPHS 512

// ---------------- degree ----------------
__global__ __launch_bounds__(256) void deg_init(float* deg, int n) {
    int i = blockIdx.x * 256 + threadIdx.x;
    if (i < n) deg[i] = 1.0f;  // self-loop
}

__global__ __launch_bounds__(256) void deg_count(const int* __restrict__ dst, float* deg, int n_edges) {
    int e = blockIdx.x * 256 + threadIdx.x;
    if (e < n_edges) atomicAdd(&deg[dst[e]], 1.0f);
}

__global__ __launch_bounds__(256) void deg_rsqrt(float* deg, int n) {
    int i = blockIdx.x * 256 + threadIdx.x;
    if (i < n) deg[i] = rsqrtf(deg[i]);  // deg >= 1 always
}

// ---------------- GEMM: xs = (X @ W) * dinv[row]; acc = xs (self-loop init) ----
template <int K>
__global__ __launch_bounds__(256) void gemm_scale(const float* __restrict__ X,
                                                  const float* __restrict__ W,
                                                  const float* __restrict__ dinv,
                                                  float* __restrict__ xs,
                                                  float* __restrict__ acc,
                                                  int n_nodes) {
    __shared__ float sW[K * 64];
    __shared__ float sX[4][K];
    int tid = threadIdx.x;
    for (int i = tid; i < K * 64; i += 256) sW[i] = W[i];
    int row0 = blockIdx.x * 4;
    for (int i = tid; i < 4 * K; i += 256) {
        int r = i / K, k = i % K;
        int rr = row0 + r;
        sX[r][k] = (rr < n_nodes) ? X[rr * K + k] : 0.0f;
    }
    __syncthreads();
    int rl = tid >> 6;        // local row 0..3
    int col = tid & 63;       // output col 0..63
    int row = row0 + rl;
    if (row >= n_nodes) return;
    float sum = 0.0f;
#pragma unroll
    for (int k = 0; k < K; ++k) sum += sX[rl][k] * sW[k * 64 + col];
    sum *= dinv[row];
    int o = row * 64 + col;
    xs[o] = sum;
    acc[o] = sum;
}

// ---------------- edge scatter: acc[dst] += xs[src] -------------------------
__global__ __launch_bounds__(256) void edge_scatter(const int* __restrict__ src,
                                                    const int* __restrict__ dst,
                                                    const float* __restrict__ xs,
                                                    float* __restrict__ acc,
                                                    int n_edges) {
    int t = blockIdx.x * 256 + threadIdx.x;   // up to 51.2M < 2^31
    int e = t >> 6;
    int f = t & 63;
    if (e >= n_edges) return;
    int s = src[e];
    int d = dst[e];
    atomicAdd(&acc[d * 64 + f], xs[s * 64 + f]);
}

// ---------------- finalize: h = relu(acc*dinv + b) --------------------------
__global__ __launch_bounds__(256) void finalize_relu(const float* __restrict__ acc,
                                                     const float* __restrict__ dinv,
                                                     const float* __restrict__ b,
                                                     float* __restrict__ h,
                                                     int n_nodes) {
    int t = blockIdx.x * 256 + threadIdx.x;
    int n = t >> 6, f = t & 63;
    if (n >= n_nodes) return;
    float v = acc[t] * dinv[n] + b[f];
    h[t] = v > 0.0f ? v : 0.0f;
}

// ---------------- finalize layer2 + mean-pool accumulation ------------------
__global__ __launch_bounds__(256) void finalize_pool(const float* __restrict__ acc,
                                                     const float* __restrict__ dinv,
                                                     const float* __restrict__ b,
                                                     const int* __restrict__ batch,
                                                     float* __restrict__ pooled,
                                                     float* __restrict__ cnts,
                                                     int n_nodes) {
    int t = blockIdx.x * 256 + threadIdx.x;
    int n = t >> 6, f = t & 63;
    if (n >= n_nodes) return;
    float v = acc[t] * dinv[n] + b[f];
    v = v > 0.0f ? v : 0.0f;
    int g = batch[n];
    atomicAdd(&pooled[g * 64 + f], v);
    if (f == 0) atomicAdd(&cnts[g], 1.0f);
}

// ---------------- head: pooled/cnt @ Wfc + bfc -> log_softmax; copy y -------
__global__ __launch_bounds__(256) void head(const float* __restrict__ pooled,
                                            const float* __restrict__ cnts,
                                            const float* __restrict__ Wfc,
                                            const float* __restrict__ bfc,
                                            const int* __restrict__ y,
                                            float* __restrict__ out,
                                            int n_graphs) {
    int g = blockIdx.x * 256 + threadIdx.x;
    if (g >= n_graphs) return;
    float c = fmaxf(cnts[g], 1.0f);
    float l0 = bfc[0], l1 = bfc[1], l2 = bfc[2], l3 = bfc[3];
#pragma unroll
    for (int k = 0; k < 64; ++k) {
        float p = pooled[g * 64 + k] / c;
        l0 += p * Wfc[k * 4 + 0];
        l1 += p * Wfc[k * 4 + 1];
        l2 += p * Wfc[k * 4 + 2];
        l3 += p * Wfc[k * 4 + 3];
    }
    float m = fmaxf(fmaxf(l0, l1), fmaxf(l2, l3));
    float s = expf(l0 - m) + expf(l1 - m) + expf(l2 - m) + expf(l3 - m);
    float lse = m + logf(s);
    out[g * 4 + 0] = l0 - lse;
    out[g * 4 + 1] = l1 - lse;
    out[g * 4 + 2] = l2 - lse;
    out[g * 4 + 3] = l3 - lse;
    out[n_graphs * 4 + g] = (float)y[g];
}

extern "C" void kernel_launch(void* const* d_in, const int* in_sizes, int n_in,
                              void* d_out, int out_size, void* d_ws, size_t ws_size,
                              hipStream_t stream) {
    const float* x   = (const float*)d_in[0];   // [50000,128]
    const int*   ei  = (const int*)d_in[1];     // [2,800000]
    const int*   batch = (const int*)d_in[2];   // [50000]
    const int*   y   = (const int*)d_in[3];     // [512]
    const float* W1  = (const float*)d_in[4];   // [128,64]
    const float* b1  = (const float*)d_in[5];   // [64]
    const float* W2  = (const float*)d_in[6];   // [64,64]
    const float* b2  = (const float*)d_in[7];   // [64]
    const float* Wfc = (const float*)d_in[8];   // [64,4]
    const float* bfc = (const float*)d_in[9];   // [4]
    float* out = (float*)d_out;                 // 512*4 logp + 512 y

    const int* src = ei;
    const int* dst = ei + N_EDGES;

    // workspace layout (float offsets)
    float* ws = (float*)d_ws;
    const size_t DINV_OFF = 0;                       // 50000
    const size_t A_OFF    = 50176;                   // 3.2M  (xs layer1 -> h1)
    const size_t B_OFF    = A_OFF + 3200000;         // 3.2M  (acc1 -> acc2)
    const size_t C_OFF    = B_OFF + 3200000;         // 3.2M  (xs layer2)
    const size_t POOL_OFF = C_OFF + 3200000;         // 512*64
    const size_t CNT_OFF  = POOL_OFF + 32768;        // 512
    float* dinv  = ws + DINV_OFF;
    float* bufA  = ws + A_OFF;
    float* bufB  = ws + B_OFF;
    float* bufC  = ws + C_OFF;
    float* pooled = ws + POOL_OFF;
    float* cnts   = ws + CNT_OFF;

    // ---- degree / dinv ----
    deg_init<<<(N_NODES + 255) / 256, 256, 0, stream>>>(dinv, N_NODES);
    deg_count<<<(N_EDGES + 255) / 256, 256, 0, stream>>>(dst, dinv, N_EDGES);
    deg_rsqrt<<<(N_NODES + 255) / 256, 256, 0, stream>>>(dinv, N_NODES);

    // ---- layer 1 ----
    gemm_scale<128><<<(N_NODES + 3) / 4, 256, 0, stream>>>(x, W1, dinv, bufA, bufB, N_NODES);
    edge_scatter<<<(N_EDGES * 64) / 256, 256, 0, stream>>>(src, dst, bufA, bufB, N_EDGES);
    finalize_relu<<<(N_NODES * 64 + 255) / 256, 256, 0, stream>>>(bufB, dinv, b1, bufA, N_NODES);

    // ---- layer 2 ----
    gemm_scale<64><<<(N_NODES + 3) / 4, 256, 0, stream>>>(bufA, W2, dinv, bufC, bufB, N_NODES);
    edge_scatter<<<(N_EDGES * 64) / 256, 256, 0, stream>>>(src, dst, bufC, bufB, N_EDGES);

    // ---- pool ----
    hipMemsetAsync(pooled, 0, (32768 + 512) * sizeof(float), stream);
    finalize_pool<<<(N_NODES * 64 + 255) / 256, 256, 0, stream>>>(bufB, dinv, b2, batch, pooled, cnts, N_NODES);

    // ---- head ----
    head<<<(N_GRAPHS + 255) / 256, 256, 0, stream>>>(pooled, cnts, Wfc, bfc, y, out, N_GRAPHS);
}

// Round 2
// 408.989 us; speedup vs baseline: 1.6353x; 1.6353x over previous
//
#include <hip/hip_runtime.h>
#include <math.h>

#define N_NODES 50000
#define N_EDGES 800000
#define N_GRAPHS 512
#define SCAN_NB ((N_NODES + 255) / 256)   // 196

// ---- histogram of dst (edge counts per node) ----
__global__ __launch_bounds__(256) void hist_k(const int* __restrict__ dst, int* __restrict__ hist, int n) {
    int e = blockIdx.x * 256 + threadIdx.x;
    if (e < n) atomicAdd(&hist[dst[e]], 1);
}

// ---- scan phase 1: per-block exclusive scan of hist; also dinv = rsqrt(1+deg) ----
__global__ __launch_bounds__(256) void scan1(const int* __restrict__ hist, int* __restrict__ offs,
                                             int* __restrict__ bsum, float* __restrict__ dinv) {
    __shared__ int sh[256];
    int t = threadIdx.x;
    int i = blockIdx.x * 256 + t;
    int v = (i < N_NODES) ? hist[i] : 0;
    if (i < N_NODES) dinv[i] = rsqrtf(1.0f + (float)v);
    sh[t] = v;
    __syncthreads();
    for (int d = 1; d < 256; d <<= 1) {
        int add = (t >= d) ? sh[t - d] : 0;
        __syncthreads();
        sh[t] += add;
        __syncthreads();
    }
    if (i < N_NODES) offs[i] = sh[t] - v;           // exclusive
    if (t == 255) bsum[blockIdx.x] = sh[255];
}

// ---- scan phase 2: scan the 196 block sums ----
__global__ __launch_bounds__(256) void scan2(const int* __restrict__ bsum, int* __restrict__ boff) {
    __shared__ int sh[256];
    int t = threadIdx.x;
    int v = (t < SCAN_NB) ? bsum[t] : 0;
    sh[t] = v;
    __syncthreads();
    for (int d = 1; d < 256; d <<= 1) {
        int add = (t >= d) ? sh[t - d] : 0;
        __syncthreads();
        sh[t] += add;
        __syncthreads();
    }
    if (t < SCAN_NB) boff[t] = sh[t] - v;
}

// ---- scan phase 3: add block offsets; init cursor; write sentinel ----
__global__ __launch_bounds__(256) void scan3(int* __restrict__ offs, const int* __restrict__ boff,
                                             int* __restrict__ cursor) {
    int i = blockIdx.x * 256 + threadIdx.x;
    if (i < N_NODES) {
        int o = offs[i] + boff[blockIdx.x];
        offs[i] = o;
        cursor[i] = o;
    }
    if (i == N_NODES - 1) offs[N_NODES] = N_EDGES;
}

// ---- reorder edges into dst-buckets ----
__global__ __launch_bounds__(256) void reorder(const int* __restrict__ src, const int* __restrict__ dst,
                                               int* __restrict__ cursor, int* __restrict__ sorted, int n) {
    int e = blockIdx.x * 256 + threadIdx.x;
    if (e < n) {
        int d = dst[e];
        int p = atomicAdd(&cursor[d], 1);
        sorted[p] = src[e];
    }
}

// ---- GEMM: xs = (X @ W) * dinv[row]; 16 rows/block, float4 W reads ----
template <int K>
__global__ __launch_bounds__(256) void gemm16(const float* __restrict__ X, const float* __restrict__ W,
                                              const float* __restrict__ dinv, float* __restrict__ xs) {
    __shared__ float sW[K * 64];
    __shared__ float sX[16][K + 1];
    int tid = threadIdx.x;
    for (int i = tid; i < K * 64; i += 256) sW[i] = W[i];
    int row0 = blockIdx.x * 16;   // 50000 % 16 == 0
    for (int i = tid; i < 16 * K; i += 256) {
        int r = i / K, k = i % K;
        sX[r][k] = X[(row0 + r) * K + k];
    }
    __syncthreads();
    int r = tid >> 4;            // 0..15
    int cg = (tid & 15) * 4;     // col group
    int row = row0 + r;
    float a0 = 0, a1 = 0, a2 = 0, a3 = 0;
#pragma unroll 8
    for (int k = 0; k < K; ++k) {
        float xv = sX[r][k];
        float4 w = *(const float4*)&sW[k * 64 + cg];
        a0 += xv * w.x; a1 += xv * w.y; a2 += xv * w.z; a3 += xv * w.w;
    }
    float s = dinv[row];
    float4 o; o.x = a0 * s; o.y = a1 * s; o.z = a2 * s; o.w = a3 * s;
    *(float4*)&xs[row * 64 + cg] = o;
}

// ---- gather-aggregate: wave per node, lane per feature; fused relu (+pool) ----
template <bool POOL>
__global__ __launch_bounds__(256) void gather_k(const float* __restrict__ xs, const int* __restrict__ offs,
                                                const int* __restrict__ sorted, const float* __restrict__ dinv,
                                                const float* __restrict__ bias, float* __restrict__ out,
                                                const int* __restrict__ batch, float* __restrict__ pooled,
                                                float* __restrict__ cnts) {
    int node = blockIdx.x * 4 + (threadIdx.x >> 6);   // 12500*4 == 50000 exact
    int f = threadIdx.x & 63;
    int beg = offs[node], end = offs[node + 1];
    float acc = xs[node * 64 + f];                    // self-loop term
    int j = beg;
    for (; j + 4 <= end; j += 4) {                    // 4-deep MLP
        int s0 = sorted[j], s1 = sorted[j + 1], s2 = sorted[j + 2], s3 = sorted[j + 3];
        float v0 = xs[s0 * 64 + f], v1 = xs[s1 * 64 + f];
        float v2 = xs[s2 * 64 + f], v3 = xs[s3 * 64 + f];
        acc += (v0 + v1) + (v2 + v3);
    }
    for (; j < end; ++j) acc += xs[sorted[j] * 64 + f];
    float v = acc * dinv[node] + bias[f];
    v = v > 0.0f ? v : 0.0f;
    if (POOL) {
        int g = batch[node];
        atomicAdd(&pooled[g * 64 + f], v);
        if (f == 0) atomicAdd(&cnts[g], 1.0f);
    } else {
        out[node * 64 + f] = v;
    }
}

// ---- head: pooled/cnt @ Wfc + bfc -> log_softmax; copy y ----
__global__ __launch_bounds__(256) void head(const float* __restrict__ pooled, const float* __restrict__ cnts,
                                            const float* __restrict__ Wfc, const float* __restrict__ bfc,
                                            const int* __restrict__ y, float* __restrict__ out, int n_graphs) {
    int g = blockIdx.x * 256 + threadIdx.x;
    if (g >= n_graphs) return;
    float c = fmaxf(cnts[g], 1.0f);
    float l0 = bfc[0], l1 = bfc[1], l2 = bfc[2], l3 = bfc[3];
#pragma unroll
    for (int k = 0; k < 64; ++k) {
        float p = pooled[g * 64 + k] / c;
        l0 += p * Wfc[k * 4 + 0];
        l1 += p * Wfc[k * 4 + 1];
        l2 += p * Wfc[k * 4 + 2];
        l3 += p * Wfc[k * 4 + 3];
    }
    float m = fmaxf(fmaxf(l0, l1), fmaxf(l2, l3));
    float s = expf(l0 - m) + expf(l1 - m) + expf(l2 - m) + expf(l3 - m);
    float lse = m + logf(s);
    out[g * 4 + 0] = l0 - lse;
    out[g * 4 + 1] = l1 - lse;
    out[g * 4 + 2] = l2 - lse;
    out[g * 4 + 3] = l3 - lse;
    out[n_graphs * 4 + g] = (float)y[g];
}

extern "C" void kernel_launch(void* const* d_in, const int* in_sizes, int n_in,
                              void* d_out, int out_size, void* d_ws, size_t ws_size,
                              hipStream_t stream) {
    const float* x     = (const float*)d_in[0];
    const int*   ei    = (const int*)d_in[1];
    const int*   batch = (const int*)d_in[2];
    const int*   y     = (const int*)d_in[3];
    const float* W1    = (const float*)d_in[4];
    const float* b1    = (const float*)d_in[5];
    const float* W2    = (const float*)d_in[6];
    const float* b2    = (const float*)d_in[7];
    const float* Wfc   = (const float*)d_in[8];
    const float* bfc   = (const float*)d_in[9];
    float* out = (float*)d_out;

    const int* src = ei;
    const int* dst = ei + N_EDGES;

    // workspace layout (4-byte units); [hist|pooled|cnts] contiguous for one memset
    char* wsb = (char*)d_ws;
    int*   hist   = (int*)wsb;                                 // 50000
    float* pooled = (float*)(wsb + 50000u * 4);                // 32768
    float* cnts   = (float*)(wsb + 82768u * 4);                // 512
    float* dinv   = (float*)(wsb + 83280u * 4);                // 50000
    int*   offs   = (int*)(wsb + 133280u * 4);                 // 50001
    int*   cursor = (int*)(wsb + 183281u * 4);                 // 50000
    int*   bsum   = (int*)(wsb + 233281u * 4);                 // 256
    int*   boff   = (int*)(wsb + 233537u * 4);                 // 256
    int*   sorted = (int*)(wsb + 233793u * 4);                 // 800000
    float* bufA   = (float*)(wsb + 1033796u * 4);              // 3.2M (16B aligned)
    float* bufB   = (float*)(wsb + 4233796u * 4);              // 3.2M (16B aligned)

    hipMemsetAsync(hist, 0, 83280u * 4, stream);               // hist + pooled + cnts

    // bucket edges by dst
    hist_k<<<N_EDGES / 256, 256, 0, stream>>>(dst, hist, N_EDGES);
    scan1<<<SCAN_NB, 256, 0, stream>>>(hist, offs, bsum, dinv);
    scan2<<<1, 256, 0, stream>>>(bsum, boff);
    scan3<<<SCAN_NB, 256, 0, stream>>>(offs, boff, cursor);
    reorder<<<N_EDGES / 256, 256, 0, stream>>>(src, dst, cursor, sorted, N_EDGES);

    // layer 1: 128 -> 64
    gemm16<128><<<N_NODES / 16, 256, 0, stream>>>(x, W1, dinv, bufA);
    gather_k<false><<<N_NODES / 4, 256, 0, stream>>>(bufA, offs, sorted, dinv, b1, bufB,
                                                     nullptr, nullptr, nullptr);
    // layer 2: 64 -> 64 (+ pool)
    gemm16<64><<<N_NODES / 16, 256, 0, stream>>>(bufB, W2, dinv, bufA);
    gather_k<true><<<N_NODES / 4, 256, 0, stream>>>(bufA, offs, sorted, dinv, b2, nullptr,
                                                    batch, pooled, cnts);

    head<<<(N_GRAPHS + 255) / 256, 256, 0, stream>>>(pooled, cnts, Wfc, bfc, y, out, N_GRAPHS);
}

// Round 3
// 390.843 us; speedup vs baseline: 1.7112x; 1.0464x over previous
//
#include <hip/hip_runtime.h>
#include <math.h>

#define N_NODES 50000
#define N_EDGES 800000
#define N_GRAPHS 512
#define SCAN_NB ((N_NODES + 255) / 256)   // 196
#define SORTED_CAP 1200000                // 800k + 50k*7 max padding

// ---- fill sorted with sentinel (zero-row index) ----
__global__ __launch_bounds__(256) void fill_k(int* __restrict__ p, int n) {
    int i = blockIdx.x * 256 + threadIdx.x;
    if (i < n) p[i] = N_NODES;            // sentinel -> zero row
}

// ---- histogram of dst ----
__global__ __launch_bounds__(256) void hist_k(const int* __restrict__ dst, int* __restrict__ hist, int n) {
    int e = blockIdx.x * 256 + threadIdx.x;
    if (e < n) atomicAdd(&hist[dst[e]], 1);
}

// ---- scan phase 1: per-block exclusive scan of PADDED deg; dinv = rsqrt(1+deg) ----
__global__ __launch_bounds__(256) void scan1(const int* __restrict__ hist, int* __restrict__ offs,
                                             int* __restrict__ bsum, float* __restrict__ dinv) {
    __shared__ int sh[256];
    int t = threadIdx.x;
    int i = blockIdx.x * 256 + t;
    int v = (i < N_NODES) ? hist[i] : 0;
    int pv = (v + 7) & ~7;                 // pad each bucket to multiple of 8
    if (i < N_NODES) dinv[i] = rsqrtf(1.0f + (float)v);
    sh[t] = pv;
    __syncthreads();
    for (int d = 1; d < 256; d <<= 1) {
        int add = (t >= d) ? sh[t - d] : 0;
        __syncthreads();
        sh[t] += add;
        __syncthreads();
    }
    if (i < N_NODES) offs[i] = sh[t] - pv; // exclusive (padded space)
    if (t == 255) bsum[blockIdx.x] = sh[255];
}

// ---- scan phase 2 ----
__global__ __launch_bounds__(256) void scan2(const int* __restrict__ bsum, int* __restrict__ boff) {
    __shared__ int sh[256];
    int t = threadIdx.x;
    int v = (t < SCAN_NB) ? bsum[t] : 0;
    sh[t] = v;
    __syncthreads();
    for (int d = 1; d < 256; d <<= 1) {
        int add = (t >= d) ? sh[t - d] : 0;
        __syncthreads();
        sh[t] += add;
        __syncthreads();
    }
    if (t < SCAN_NB) boff[t] = sh[t] - v;
}

// ---- scan phase 3: add block offsets; init cursor; sentinel; zero rows ----
__global__ __launch_bounds__(256) void scan3(int* __restrict__ offs, const int* __restrict__ boff,
                                             int* __restrict__ cursor, const int* __restrict__ hist,
                                             float* __restrict__ bufA, float* __restrict__ bufB) {
    int i = blockIdx.x * 256 + threadIdx.x;
    if (i < N_NODES) {
        int o = offs[i] + boff[blockIdx.x];
        offs[i] = o;
        cursor[i] = o;
        if (i == N_NODES - 1) offs[N_NODES] = o + ((hist[i] + 7) & ~7);
    } else {
        int r = i - N_NODES;               // last block: spare threads zero row 50000
        if (r < 64) bufA[N_NODES * 64 + r] = 0.0f;
        else if (r < 128) bufB[N_NODES * 64 + (r - 64)] = 0.0f;
    }
}

// ---- reorder edges into padded dst-buckets ----
__global__ __launch_bounds__(256) void reorder(const int* __restrict__ src, const int* __restrict__ dst,
                                               int* __restrict__ cursor, int* __restrict__ sorted, int n) {
    int e = blockIdx.x * 256 + threadIdx.x;
    if (e < n) {
        int d = dst[e];
        int p = atomicAdd(&cursor[d], 1);
        sorted[p] = src[e];
    }
}

// ---- GEMM: xs = (X @ W) * dinv[row] ----
template <int K>
__global__ __launch_bounds__(256) void gemm16(const float* __restrict__ X, const float* __restrict__ W,
                                              const float* __restrict__ dinv, float* __restrict__ xs) {
    __shared__ float sW[K * 64];
    __shared__ float sX[16][K + 1];
    int tid = threadIdx.x;
    for (int i = tid; i < K * 64; i += 256) sW[i] = W[i];
    int row0 = blockIdx.x * 16;   // 50000 % 16 == 0
    for (int i = tid; i < 16 * K; i += 256) {
        int r = i / K, k = i % K;
        sX[r][k] = X[(row0 + r) * K + k];
    }
    __syncthreads();
    int r = tid >> 4;
    int cg = (tid & 15) * 4;
    int row = row0 + r;
    float a0 = 0, a1 = 0, a2 = 0, a3 = 0;
#pragma unroll 8
    for (int k = 0; k < K; ++k) {
        float xv = sX[r][k];
        float4 w = *(const float4*)&sW[k * 64 + cg];
        a0 += xv * w.x; a1 += xv * w.y; a2 += xv * w.z; a3 += xv * w.w;
    }
    float s = dinv[row];
    float4 o; o.x = a0 * s; o.y = a1 * s; o.z = a2 * s; o.w = a3 * s;
    *(float4*)&xs[row * 64 + cg] = o;
}

// ---- gather-aggregate: wave/node, lane/feature, 8-deep pipelined batches ----
template <bool POOL>
__global__ __launch_bounds__(256) void gather_k(const float* __restrict__ xs, const int* __restrict__ offs,
                                                const int* __restrict__ sorted, const float* __restrict__ dinv,
                                                const float* __restrict__ bias, float* __restrict__ out,
                                                const int* __restrict__ batch, float* __restrict__ pooled,
                                                float* __restrict__ cnts) {
    int node = blockIdx.x * 4 + (threadIdx.x >> 6);   // 12500*4 == 50000 exact
    int f = threadIdx.x & 63;
    int beg = offs[node], end = offs[node + 1];       // beg,end multiples of 8
    float acc = xs[node * 64 + f];                    // self-loop term
    int nb = (end - beg) >> 3;
    const int4* sp = (const int4*)(sorted + beg);     // 16B-aligned (beg%8==0)
    if (nb > 0) {
        int4 ia = sp[0], ib = sp[1];
        for (int it = 0; it < nb; ++it) {
            int4 na = ia, nb4 = ib;
            if (it + 1 < nb) { na = sp[2 * it + 2]; nb4 = sp[2 * it + 3]; }
            float v0 = xs[ia.x * 64 + f];
            float v1 = xs[ia.y * 64 + f];
            float v2 = xs[ia.z * 64 + f];
            float v3 = xs[ia.w * 64 + f];
            float v4 = xs[ib.x * 64 + f];
            float v5 = xs[ib.y * 64 + f];
            float v6 = xs[ib.z * 64 + f];
            float v7 = xs[ib.w * 64 + f];
            acc += ((v0 + v1) + (v2 + v3)) + ((v4 + v5) + (v6 + v7));
            ia = na; ib = nb4;
        }
    }
    float v = acc * dinv[node] + bias[f];
    v = v > 0.0f ? v : 0.0f;
    if (POOL) {
        int g = batch[node];
        atomicAdd(&pooled[g * 64 + f], v);
        if (f == 0) atomicAdd(&cnts[g], 1.0f);
    } else {
        out[node * 64 + f] = v;
    }
}

// ---- head ----
__global__ __launch_bounds__(256) void head(const float* __restrict__ pooled, const float* __restrict__ cnts,
                                            const float* __restrict__ Wfc, const float* __restrict__ bfc,
                                            const int* __restrict__ y, float* __restrict__ out, int n_graphs) {
    int g = blockIdx.x * 256 + threadIdx.x;
    if (g >= n_graphs) return;
    float c = fmaxf(cnts[g], 1.0f);
    float l0 = bfc[0], l1 = bfc[1], l2 = bfc[2], l3 = bfc[3];
#pragma unroll
    for (int k = 0; k < 64; ++k) {
        float p = pooled[g * 64 + k] / c;
        l0 += p * Wfc[k * 4 + 0];
        l1 += p * Wfc[k * 4 + 1];
        l2 += p * Wfc[k * 4 + 2];
        l3 += p * Wfc[k * 4 + 3];
    }
    float m = fmaxf(fmaxf(l0, l1), fmaxf(l2, l3));
    float s = expf(l0 - m) + expf(l1 - m) + expf(l2 - m) + expf(l3 - m);
    float lse = m + logf(s);
    out[g * 4 + 0] = l0 - lse;
    out[g * 4 + 1] = l1 - lse;
    out[g * 4 + 2] = l2 - lse;
    out[g * 4 + 3] = l3 - lse;
    out[n_graphs * 4 + g] = (float)y[g];
}

extern "C" void kernel_launch(void* const* d_in, const int* in_sizes, int n_in,
                              void* d_out, int out_size, void* d_ws, size_t ws_size,
                              hipStream_t stream) {
    const float* x     = (const float*)d_in[0];
    const int*   ei    = (const int*)d_in[1];
    const int*   batch = (const int*)d_in[2];
    const int*   y     = (const int*)d_in[3];
    const float* W1    = (const float*)d_in[4];
    const float* b1    = (const float*)d_in[5];
    const float* W2    = (const float*)d_in[6];
    const float* b2    = (const float*)d_in[7];
    const float* Wfc   = (const float*)d_in[8];
    const float* bfc   = (const float*)d_in[9];
    float* out = (float*)d_out;

    const int* src = ei;
    const int* dst = ei + N_EDGES;

    // workspace (element offsets, all 16B-aligned where it matters)
    char* wsb = (char*)d_ws;
    int*   hist   = (int*)wsb;                                  // 50000
    float* pooled = (float*)(wsb + 50000u * 4);                 // 32768
    float* cnts   = (float*)(wsb + 82768u * 4);                 // 512
    float* dinv   = (float*)(wsb + 83280u * 4);                 // 50000
    int*   offs   = (int*)(wsb + 133280u * 4);                  // 50001
    int*   cursor = (int*)(wsb + 183284u * 4);                  // 50000
    int*   bsum   = (int*)(wsb + 233284u * 4);                  // 256
    int*   boff   = (int*)(wsb + 233540u * 4);                  // 256
    int*   sorted = (int*)(wsb + 233796u * 4);                  // 1.2M (16B aligned)
    float* bufA   = (float*)(wsb + 1433796u * 4);               // (50001)*64
    float* bufB   = (float*)(wsb + 4633860u * 4);               // (50001)*64

    hipMemsetAsync(hist, 0, 83280u * 4, stream);                // hist+pooled+cnts
    fill_k<<<(SORTED_CAP + 255) / 256, 256, 0, stream>>>(sorted, SORTED_CAP);

    hist_k<<<N_EDGES / 256, 256, 0, stream>>>(dst, hist, N_EDGES);
    scan1<<<SCAN_NB, 256, 0, stream>>>(hist, offs, bsum, dinv);
    scan2<<<1, 256, 0, stream>>>(bsum, boff);
    scan3<<<SCAN_NB, 256, 0, stream>>>(offs, boff, cursor, hist, bufA, bufB);
    reorder<<<N_EDGES / 256, 256, 0, stream>>>(src, dst, cursor, sorted, N_EDGES);

    // layer 1: 128 -> 64
    gemm16<128><<<N_NODES / 16, 256, 0, stream>>>(x, W1, dinv, bufA);
    gather_k<false><<<N_NODES / 4, 256, 0, stream>>>(bufA, offs, sorted, dinv, b1, bufB,
                                                     nullptr, nullptr, nullptr);
    // layer 2: 64 -> 64 (+ pool)
    gemm16<64><<<N_NODES / 16, 256, 0, stream>>>(bufB, W2, dinv, bufA);
    gather_k<true><<<N_NODES / 4, 256, 0, stream>>>(bufA, offs, sorted, dinv, b2, nullptr,
                                                    batch, pooled, cnts);

    head<<<(N_GRAPHS + 255) / 256, 256, 0, stream>>>(pooled, cnts, Wfc, bfc, y, out, N_GRAPHS);
}

// Round 4
// 357.047 us; speedup vs baseline: 1.8732x; 1.0947x over previous
//
#include <hip/hip_runtime.h>
#include <hip/hip_fp16.h>
#include <math.h>

#define N_NODES 50000
#define N_EDGES 800000
#define N_GRAPHS 512
#define SCAN_NB ((N_NODES + 255) / 256)   // 196
#define SORTED_CAP 1550000                // 800k + 50k*15 max padding (pad-16)

// ---- fill sorted with sentinel (zero-row index) ----
__global__ __launch_bounds__(256) void fill_k(int* __restrict__ p, int n) {
    int i = blockIdx.x * 256 + threadIdx.x;
    if (i < n) p[i] = N_NODES;            // sentinel -> zero row
}

// ---- histogram of dst ----
__global__ __launch_bounds__(256) void hist_k(const int* __restrict__ dst, int* __restrict__ hist, int n) {
    int e = blockIdx.x * 256 + threadIdx.x;
    if (e < n) atomicAdd(&hist[dst[e]], 1);
}

// ---- scan phase 1: per-block exclusive scan of PADDED deg; dinv = rsqrt(1+deg) ----
__global__ __launch_bounds__(256) void scan1(const int* __restrict__ hist, int* __restrict__ offs,
                                             int* __restrict__ bsum, float* __restrict__ dinv) {
    __shared__ int sh[256];
    int t = threadIdx.x;
    int i = blockIdx.x * 256 + t;
    int v = (i < N_NODES) ? hist[i] : 0;
    int pv = (v + 15) & ~15;               // pad each bucket to multiple of 16
    if (i < N_NODES) dinv[i] = rsqrtf(1.0f + (float)v);
    sh[t] = pv;
    __syncthreads();
    for (int d = 1; d < 256; d <<= 1) {
        int add = (t >= d) ? sh[t - d] : 0;
        __syncthreads();
        sh[t] += add;
        __syncthreads();
    }
    if (i < N_NODES) offs[i] = sh[t] - pv; // exclusive (padded space)
    if (t == 255) bsum[blockIdx.x] = sh[255];
}

// ---- scan phase 2 ----
__global__ __launch_bounds__(256) void scan2(const int* __restrict__ bsum, int* __restrict__ boff) {
    __shared__ int sh[256];
    int t = threadIdx.x;
    int v = (t < SCAN_NB) ? bsum[t] : 0;
    sh[t] = v;
    __syncthreads();
    for (int d = 1; d < 256; d <<= 1) {
        int add = (t >= d) ? sh[t - d] : 0;
        __syncthreads();
        sh[t] += add;
        __syncthreads();
    }
    if (t < SCAN_NB) boff[t] = sh[t] - v;
}

// ---- scan phase 3: add block offsets; init cursor; sentinel; zero half-rows ----
__global__ __launch_bounds__(256) void scan3(int* __restrict__ offs, const int* __restrict__ boff,
                                             int* __restrict__ cursor, const int* __restrict__ hist,
                                             unsigned short* __restrict__ xsh1,
                                             unsigned short* __restrict__ xsh2) {
    int i = blockIdx.x * 256 + threadIdx.x;
    if (i < N_NODES) {
        int o = offs[i] + boff[blockIdx.x];
        offs[i] = o;
        cursor[i] = o;
        if (i == N_NODES - 1) offs[N_NODES] = o + ((hist[i] + 15) & ~15);
    } else {
        int r = i - N_NODES;               // spare threads zero row 50000 of both tables
        if (r < 64) xsh1[N_NODES * 64 + r] = 0;
        else if (r < 128) xsh2[N_NODES * 64 + (r - 64)] = 0;
    }
}

// ---- reorder edges into padded dst-buckets ----
__global__ __launch_bounds__(256) void reorder(const int* __restrict__ src, const int* __restrict__ dst,
                                               int* __restrict__ cursor, int* __restrict__ sorted, int n) {
    int e = blockIdx.x * 256 + threadIdx.x;
    if (e < n) {
        int d = dst[e];
        int p = atomicAdd(&cursor[d], 1);
        sorted[p] = src[e];
    }
}

// ---- GEMM: xsh = fp16((X @ W) * dinv[row]) ----
template <int K>
__global__ __launch_bounds__(256) void gemm16(const float* __restrict__ X, const float* __restrict__ W,
                                              const float* __restrict__ dinv, __half* __restrict__ xsh) {
    __shared__ float sW[K * 64];
    __shared__ float sX[16][K + 1];
    int tid = threadIdx.x;
    for (int i = tid; i < K * 64; i += 256) sW[i] = W[i];
    int row0 = blockIdx.x * 16;   // 50000 % 16 == 0
    for (int i = tid; i < 16 * K; i += 256) {
        int r = i / K, k = i % K;
        sX[r][k] = X[(row0 + r) * K + k];
    }
    __syncthreads();
    int r = tid >> 4;
    int cg = (tid & 15) * 4;
    int row = row0 + r;
    float a0 = 0, a1 = 0, a2 = 0, a3 = 0;
#pragma unroll 8
    for (int k = 0; k < K; ++k) {
        float xv = sX[r][k];
        float4 w = *(const float4*)&sW[k * 64 + cg];
        a0 += xv * w.x; a1 += xv * w.y; a2 += xv * w.z; a3 += xv * w.w;
    }
    float s = dinv[row];
    __half2 lo = __floats2half2_rn(a0 * s, a1 * s);
    __half2 hi = __floats2half2_rn(a2 * s, a3 * s);
    uint2 pk;
    pk.x = *(const unsigned int*)&lo;
    pk.y = *(const unsigned int*)&hi;
    *(uint2*)&xsh[row * 64 + cg] = pk;     // 8B aligned (cg % 4 == 0)
}

// ---- gather: wave/node; lanes 0-31 = edge A, lanes 32-63 = edge B; half2/lane ----
template <bool POOL>
__global__ __launch_bounds__(256) void gather_h(const __half2* __restrict__ xs2, const int* __restrict__ offs,
                                                const int* __restrict__ sorted, const float* __restrict__ dinv,
                                                const float2* __restrict__ bias2, float2* __restrict__ out,
                                                const int* __restrict__ batch, float* __restrict__ pooled,
                                                float* __restrict__ cnts) {
    int node = blockIdx.x * 4 + (threadIdx.x >> 6);   // 12500*4 == 50000 exact
    int lane = threadIdx.x & 63;
    int hb = lane >> 5;                               // 0 = half-wave A, 1 = B
    int fl = lane & 31;                               // feature pair index
    int beg = offs[node], end = offs[node + 1];       // multiples of 16
    float2 acc;
    if (hb == 0) {                                    // self-loop in half A
        float2 v = __half22float2(xs2[node * 32 + fl]);
        acc.x = v.x; acc.y = v.y;
    } else {
        acc.x = 0.0f; acc.y = 0.0f;
    }
    int nit = (end - beg) >> 4;
    const int4* sp = (const int4*)(sorted + beg);     // 16B-aligned (beg % 16 == 0)
    if (nit > 0) {
        int4 A0 = sp[0], A1 = sp[1], B0 = sp[2], B1 = sp[3];
        for (int it = 0; it < nit; ++it) {
            int4 nA0 = A0, nA1 = A1, nB0 = B0, nB1 = B1;
            if (it + 1 < nit) {
                nA0 = sp[4 * it + 4]; nA1 = sp[4 * it + 5];
                nB0 = sp[4 * it + 6]; nB1 = sp[4 * it + 7];
            }
            int i0 = hb ? B0.x : A0.x;
            int i1 = hb ? B0.y : A0.y;
            int i2 = hb ? B0.z : A0.z;
            int i3 = hb ? B0.w : A0.w;
            int i4 = hb ? B1.x : A1.x;
            int i5 = hb ? B1.y : A1.y;
            int i6 = hb ? B1.z : A1.z;
            int i7 = hb ? B1.w : A1.w;
            float2 v0 = __half22float2(xs2[i0 * 32 + fl]);
            float2 v1 = __half22float2(xs2[i1 * 32 + fl]);
            float2 v2 = __half22float2(xs2[i2 * 32 + fl]);
            float2 v3 = __half22float2(xs2[i3 * 32 + fl]);
            float2 v4 = __half22float2(xs2[i4 * 32 + fl]);
            float2 v5 = __half22float2(xs2[i5 * 32 + fl]);
            float2 v6 = __half22float2(xs2[i6 * 32 + fl]);
            float2 v7 = __half22float2(xs2[i7 * 32 + fl]);
            acc.x += ((v0.x + v1.x) + (v2.x + v3.x)) + ((v4.x + v5.x) + (v6.x + v7.x));
            acc.y += ((v0.y + v1.y) + (v2.y + v3.y)) + ((v4.y + v5.y) + (v6.y + v7.y));
            A0 = nA0; A1 = nA1; B0 = nB0; B1 = nB1;
        }
    }
    // combine the two half-wave partial sums
    acc.x += __shfl_xor(acc.x, 32);
    acc.y += __shfl_xor(acc.y, 32);
    if (hb == 0) {
        float d = dinv[node];
        float2 b = bias2[fl];
        float v0 = acc.x * d + b.x;
        float v1 = acc.y * d + b.y;
        v0 = v0 > 0.0f ? v0 : 0.0f;
        v1 = v1 > 0.0f ? v1 : 0.0f;
        if (POOL) {
            int g = batch[node];
            atomicAdd(&pooled[g * 64 + 2 * fl], v0);
            atomicAdd(&pooled[g * 64 + 2 * fl + 1], v1);
            if (fl == 0) atomicAdd(&cnts[g], 1.0f);
        } else {
            float2 o; o.x = v0; o.y = v1;
            out[node * 32 + fl] = o;
        }
    }
}

// ---- head ----
__global__ __launch_bounds__(256) void head(const float* __restrict__ pooled, const float* __restrict__ cnts,
                                            const float* __restrict__ Wfc, const float* __restrict__ bfc,
                                            const int* __restrict__ y, float* __restrict__ out, int n_graphs) {
    int g = blockIdx.x * 256 + threadIdx.x;
    if (g >= n_graphs) return;
    float c = fmaxf(cnts[g], 1.0f);
    float l0 = bfc[0], l1 = bfc[1], l2 = bfc[2], l3 = bfc[3];
#pragma unroll
    for (int k = 0; k < 64; ++k) {
        float p = pooled[g * 64 + k] / c;
        l0 += p * Wfc[k * 4 + 0];
        l1 += p * Wfc[k * 4 + 1];
        l2 += p * Wfc[k * 4 + 2];
        l3 += p * Wfc[k * 4 + 3];
    }
    float m = fmaxf(fmaxf(l0, l1), fmaxf(l2, l3));
    float s = expf(l0 - m) + expf(l1 - m) + expf(l2 - m) + expf(l3 - m);
    float lse = m + logf(s);
    out[g * 4 + 0] = l0 - lse;
    out[g * 4 + 1] = l1 - lse;
    out[g * 4 + 2] = l2 - lse;
    out[g * 4 + 3] = l3 - lse;
    out[n_graphs * 4 + g] = (float)y[g];
}

extern "C" void kernel_launch(void* const* d_in, const int* in_sizes, int n_in,
                              void* d_out, int out_size, void* d_ws, size_t ws_size,
                              hipStream_t stream) {
    const float* x     = (const float*)d_in[0];
    const int*   ei    = (const int*)d_in[1];
    const int*   batch = (const int*)d_in[2];
    const int*   y     = (const int*)d_in[3];
    const float* W1    = (const float*)d_in[4];
    const float* b1    = (const float*)d_in[5];
    const float* W2    = (const float*)d_in[6];
    const float* b2    = (const float*)d_in[7];
    const float* Wfc   = (const float*)d_in[8];
    const float* bfc   = (const float*)d_in[9];
    float* out = (float*)d_out;

    const int* src = ei;
    const int* dst = ei + N_EDGES;

    // workspace layout (byte offsets; all vector accesses 16B-aligned)
    char* wsb = (char*)d_ws;
    int*   hist   = (int*)wsb;                                  // 50000 ints
    float* pooled = (float*)(wsb + 50000u * 4);                 // 32768
    float* cnts   = (float*)(wsb + 82768u * 4);                 // 512
    float* dinv   = (float*)(wsb + 83280u * 4);                 // 50000
    int*   offs   = (int*)(wsb + 133280u * 4);                  // 50001
    int*   cursor = (int*)(wsb + 183284u * 4);                  // 50000
    int*   bsum   = (int*)(wsb + 233284u * 4);                  // 256
    int*   boff   = (int*)(wsb + 233540u * 4);                  // 256
    int*   sorted = (int*)(wsb + 233796u * 4);                  // 1.55M ints
    __half* xsh1  = (__half*)(wsb + 7135184u);                  // 50001*64 halves (16B aligned)
    __half* xsh2  = (__half*)(wsb + 13535312u);                 // 50001*64 halves (16B aligned)
    float* bufB   = (float*)(wsb + 19935440u);                  // 50000*64 fp32 (h1)

    hipMemsetAsync(hist, 0, 83280u * 4, stream);                // hist+pooled+cnts
    fill_k<<<(SORTED_CAP + 255) / 256, 256, 0, stream>>>(sorted, SORTED_CAP);

    hist_k<<<N_EDGES / 256, 256, 0, stream>>>(dst, hist, N_EDGES);
    scan1<<<SCAN_NB, 256, 0, stream>>>(hist, offs, bsum, dinv);
    scan2<<<1, 256, 0, stream>>>(bsum, boff);
    scan3<<<SCAN_NB, 256, 0, stream>>>(offs, boff, cursor, hist,
                                       (unsigned short*)xsh1, (unsigned short*)xsh2);
    reorder<<<N_EDGES / 256, 256, 0, stream>>>(src, dst, cursor, sorted, N_EDGES);

    // layer 1: 128 -> 64
    gemm16<128><<<N_NODES / 16, 256, 0, stream>>>(x, W1, dinv, xsh1);
    gather_h<false><<<N_NODES / 4, 256, 0, stream>>>((const __half2*)xsh1, offs, sorted, dinv,
                                                     (const float2*)b1, (float2*)bufB,
                                                     nullptr, nullptr, nullptr);
    // layer 2: 64 -> 64 (+ pool)
    gemm16<64><<<N_NODES / 16, 256, 0, stream>>>(bufB, W2, dinv, xsh2);
    gather_h<true><<<N_NODES / 4, 256, 0, stream>>>((const __half2*)xsh2, offs, sorted, dinv,
                                                    (const float2*)b2, nullptr,
                                                    batch, pooled, cnts);

    head<<<(N_GRAPHS + 255) / 256, 256, 0, stream>>>(pooled, cnts, Wfc, bfc, y, out, N_GRAPHS);
}